// Round 1
// baseline (1168.286 us; speedup 1.0000x reference)
//
#include <hip/hip_runtime.h>
#include <math.h>

// ---------------- device helpers ----------------
__device__ __forceinline__ int dev_lower_bound(const int* __restrict__ a, int n, int v){
  int lo = 0, hi = n;
  while (lo < hi){ int mid = (lo + hi) >> 1; if (a[mid] < v) lo = mid + 1; else hi = mid; }
  return lo;
}

// ---------------- CSR build ----------------
__global__ void init_deg_kernel(int* __restrict__ deg, int n){
  int i = blockIdx.x * blockDim.x + threadIdx.x;
  if (i < n) deg[i] = 1;            // self-loop contributes 1 to every node
}

__global__ void hist_kernel(const int* __restrict__ dst, int* __restrict__ deg, int nE){
  int e = blockIdx.x * blockDim.x + threadIdx.x;
  if (e < nE) atomicAdd(&deg[dst[e]], 1);
}

__global__ __launch_bounds__(1024) void scan_kernel(const int* __restrict__ deg,
    int* __restrict__ row_off, int* __restrict__ cursor, int n){
  __shared__ int sums[1024];
  int tid = threadIdx.x;
  int chunk = (n + 1023) >> 10;
  int beg = tid * chunk;
  int end = min(beg + chunk, n);
  int s = 0;
  for (int i = beg; i < end; ++i) s += deg[i];
  sums[tid] = s;
  __syncthreads();
  for (int off = 1; off < 1024; off <<= 1){
    int v = (tid >= off) ? sums[tid - off] : 0;
    __syncthreads();
    sums[tid] += v;
    __syncthreads();
  }
  int run = (tid == 0) ? 0 : sums[tid - 1];
  for (int i = beg; i < end; ++i){ row_off[i] = run; cursor[i] = run; run += deg[i]; }
  if (tid == 0) row_off[n] = sums[1023];
}

__global__ void scatter_kernel(const int* __restrict__ src, const int* __restrict__ dst,
    int* __restrict__ cursor, int* __restrict__ csr_src, int nE, int n){
  int e = blockIdx.x * blockDim.x + threadIdx.x;
  if (e < nE){
    int pos = atomicAdd(&cursor[dst[e]], 1);
    csr_src[pos] = src[e];
  } else if (e < nE + n){
    int i = e - nE;                  // self loop i -> i
    int pos = atomicAdd(&cursor[i], 1);
    csr_src[pos] = i;
  }
}

// ---------------- fused xl/xr GEMM: out = X @ W + b ----------------
// X:[n,128] row-major, W:[128(fi),128(fo)] row-major. blockIdx.y picks (Wl,bl,xl) vs (Wr,br,xr).
// 512 threads; 128-row x 128-col tile; K staged in chunks of 32 (LDS ~34.4 KB).
__global__ __launch_bounds__(512) void gemm_xlxr_kernel(
    const float* __restrict__ X,
    const float* __restrict__ Wl, const float* __restrict__ bl,
    const float* __restrict__ Wr, const float* __restrict__ br,
    float* __restrict__ xl, float* __restrict__ xr, int n)
{
  const float* W; const float* b; float* out;
  if (blockIdx.y == 0){ W = Wl; b = bl; out = xl; } else { W = Wr; b = br; out = xr; }
  __shared__ float Ws[32][128];      // 16 KB
  __shared__ float Xs[128][36];      // 18.4 KB (pad 36: float4-aligned, bank-spread)
  const int tid = threadIdx.x;
  const int row0 = blockIdx.x * 128;
  const int tc = tid & 31;           // 4 output cols: 4*tc..4*tc+3
  const int tr = tid >> 5;           // 8 rows: 8*tr..8*tr+7
  float acc[8][4] = {};
  for (int kc = 0; kc < 128; kc += 32){
    for (int idx = tid; idx < 1024; idx += 512){          // W chunk: 32x128
      int r = idx >> 5, c4 = idx & 31;
      *(float4*)(&Ws[r][c4 * 4]) = *(const float4*)(W + (size_t)(kc + r) * 128 + c4 * 4);
    }
    for (int idx = tid; idx < 1024; idx += 512){          // X chunk: 128x32
      int r = idx >> 3, c4 = idx & 7;
      int grow = row0 + r;
      float4 v = make_float4(0.f, 0.f, 0.f, 0.f);
      if (grow < n) v = *(const float4*)(X + (size_t)grow * 128 + kc + c4 * 4);
      *(float4*)(&Xs[r][c4 * 4]) = v;
    }
    __syncthreads();
    #pragma unroll
    for (int k = 0; k < 32; ++k){
      float4 w = *(const float4*)(&Ws[k][tc * 4]);
      #pragma unroll
      for (int r = 0; r < 8; ++r){
        float xv = Xs[tr * 8 + r][k];                     // half-wave broadcast
        acc[r][0] = fmaf(xv, w.x, acc[r][0]);
        acc[r][1] = fmaf(xv, w.y, acc[r][1]);
        acc[r][2] = fmaf(xv, w.z, acc[r][2]);
        acc[r][3] = fmaf(xv, w.w, acc[r][3]);
      }
    }
    __syncthreads();
  }
  float4 bv = *(const float4*)(b + tc * 4);
  #pragma unroll
  for (int r = 0; r < 8; ++r){
    int grow = row0 + tr * 8 + r;
    if (grow < n){
      float4 o = make_float4(acc[r][0] + bv.x, acc[r][1] + bv.y,
                             acc[r][2] + bv.z, acc[r][3] + bv.w);
      *(float4*)(out + (size_t)grow * 128 + tc * 4) = o;
    }
  }
}

// ---------------- per-destination online-softmax attention ----------------
// One 64-lane wave per destination node; each lane owns 2 of 128 feature cols.
// Single pass over in-edges: score + online softmax + weighted accumulate.
__global__ __launch_bounds__(256) void edge_attn_kernel(
    const float* __restrict__ xl, const float* __restrict__ xr,
    const int* __restrict__ row_off, const int* __restrict__ csr_src,
    const float* __restrict__ att, const float* __restrict__ bias,
    float* __restrict__ out, int n, int do_relu)
{
  int gtid = blockIdx.x * blockDim.x + threadIdx.x;
  int wid = gtid >> 6;               // one wave per dst node
  int lane = threadIdx.x & 63;
  if (wid >= n) return;
  const float2 xrv  = *(const float2*)(xr  + (size_t)wid * 128 + lane * 2);
  const float2 attv = *(const float2*)(att + lane * 2);
  int p = row_off[wid];
  const int pend = row_off[wid + 1];
  float m = -3.0e38f, s = 0.f, acc0 = 0.f, acc1 = 0.f;
  for (; p < pend; ++p){
    int sidx = csr_src[p];
    float2 xlv = *(const float2*)(xl + (size_t)sidx * 128 + lane * 2);
    float t0 = xlv.x + xrv.x; t0 = fmaxf(t0, 0.2f * t0);   // leaky_relu, slope .2
    float t1 = xlv.y + xrv.y; t1 = fmaxf(t1, 0.2f * t1);
    float part = t0 * attv.x + t1 * attv.y;
    #pragma unroll
    for (int off = 32; off > 0; off >>= 1) part += __shfl_xor(part, off);
    // part == full 128-dim score, uniform across lanes -> branch-free online softmax
    float mnew  = fmaxf(m, part);
    float scale = __expf(m - mnew);      // m==-3e38 first iter -> 0
    float pp    = __expf(part - mnew);
    s    = s    * scale + pp;
    acc0 = acc0 * scale + pp * xlv.x;
    acc1 = acc1 * scale + pp * xlv.y;
    m = mnew;
  }
  float inv = 1.0f / s;                  // self-loop guarantees s > 0
  float2 bv = *(const float2*)(bias + lane * 2);
  float o0 = acc0 * inv + bv.x;
  float o1 = acc1 * inv + bv.y;
  if (do_relu){ o0 = fmaxf(o0, 0.f); o1 = fmaxf(o1, 0.f); }
  *(float2*)(out + (size_t)wid * 128 + lane * 2) = make_float2(o0, o1);
}

// ---------------- mean-pool + MLP head ----------------
__global__ __launch_bounds__(128) void pool_mlp_kernel(
    const float* __restrict__ h, const int* __restrict__ batch, int n,
    const float* __restrict__ W4, const float* __restrict__ b4,
    const float* __restrict__ W5, const float* __restrict__ b5,
    const float* __restrict__ W6, const float* __restrict__ b6,
    float* __restrict__ out)
{
  int g = blockIdx.x;                  // one block per graph
  int t = threadIdx.x;                 // 128 threads = feature cols
  __shared__ float gf[128];
  __shared__ float h1[128];
  __shared__ float h2[64];
  int lo = dev_lower_bound(batch, n, g);
  int hi = dev_lower_bound(batch, n, g + 1);
  float ssum = 0.f;
  for (int i = lo; i < hi; ++i) ssum += h[(size_t)i * 128 + t];
  float cnt = (float)(hi - lo);
  gf[t] = ssum / fmaxf(cnt, 1.0f);
  __syncthreads();
  float a = b4[t];
  for (int k = 0; k < 128; ++k) a = fmaf(gf[k], W4[k * 128 + t], a);
  h1[t] = 1.0f / (1.0f + __expf(-a));
  __syncthreads();
  if (t < 64){
    float a5 = b5[t];
    for (int k = 0; k < 128; ++k) a5 = fmaf(h1[k], W5[k * 64 + t], a5);
    h2[t] = 1.0f / (1.0f + __expf(-a5));
  }
  __syncthreads();
  if (t < 2){
    float a6 = b6[t];
    for (int k = 0; k < 64; ++k) a6 = fmaf(h2[k], W6[k * 2 + t], a6);
    out[g * 2 + t] = a6;
  }
}

// ---------------- launcher ----------------
extern "C" void kernel_launch(void* const* d_in, const int* in_sizes, int n_in,
                              void* d_out, int out_size, void* d_ws, size_t ws_size,
                              hipStream_t stream)
{
  const float* x          = (const float*)d_in[0];
  const int*   edge_index = (const int*)d_in[1];
  const int*   batch      = (const int*)d_in[2];
  const int n  = in_sizes[0] / 128;            // 50000
  const int nE = in_sizes[1] / 2;              // 1600000
  const int* esrc = edge_index;
  const int* edst = edge_index + nE;
  const int n_graphs = out_size / 2;           // 512

  const float *Wl[3], *bl[3], *Wr[3], *br[3], *att[3], *bias[3];
  for (int l = 0; l < 3; ++l){
    Wl[l]   = (const float*)d_in[3 + 6 * l + 0];
    bl[l]   = (const float*)d_in[3 + 6 * l + 1];
    Wr[l]   = (const float*)d_in[3 + 6 * l + 2];
    br[l]   = (const float*)d_in[3 + 6 * l + 3];
    att[l]  = (const float*)d_in[3 + 6 * l + 4];
    bias[l] = (const float*)d_in[3 + 6 * l + 5];
  }
  const float* W4 = (const float*)d_in[21]; const float* b4 = (const float*)d_in[22];
  const float* W5 = (const float*)d_in[23]; const float* b5 = (const float*)d_in[24];
  const float* W6 = (const float*)d_in[25]; const float* b6 = (const float*)d_in[26];

  // workspace carve (bump allocator, 256B aligned). Total ~110 MB.
  char* ws = (char*)d_ws;
  size_t off = 0;
  auto alloc = [&](size_t bytes) -> void* {
    void* p = ws + off;
    off = (off + bytes + 255) & ~(size_t)255;
    return p;
  };
  int*   row_off = (int*)  alloc((size_t)(n + 1) * sizeof(int));
  int*   deg     = (int*)  alloc((size_t)n * sizeof(int));
  int*   cursor  = (int*)  alloc((size_t)n * sizeof(int));
  int*   csr_src = (int*)  alloc((size_t)(nE + n) * sizeof(int));
  float* xlb     = (float*)alloc((size_t)n * 128 * sizeof(float));
  float* xrb     = (float*)alloc((size_t)n * 128 * sizeof(float));
  float* hC      = (float*)alloc((size_t)n * 128 * sizeof(float));
  float* hD      = (float*)alloc((size_t)n * 128 * sizeof(float));
  (void)ws_size; (void)n_in;

  // CSR build (by destination)
  init_deg_kernel<<<(n + 255) / 256, 256, 0, stream>>>(deg, n);
  hist_kernel<<<(nE + 255) / 256, 256, 0, stream>>>(edst, deg, nE);
  scan_kernel<<<1, 1024, 0, stream>>>(deg, row_off, cursor, n);
  scatter_kernel<<<(nE + n + 255) / 256, 256, 0, stream>>>(esrc, edst, cursor, csr_src, nE, n);

  // 3 GATv2 layers
  const float* hin = x;
  float* outs[3] = { hC, hD, hC };
  for (int l = 0; l < 3; ++l){
    dim3 ggrid((n + 127) / 128, 2);
    gemm_xlxr_kernel<<<ggrid, 512, 0, stream>>>(hin, Wl[l], bl[l], Wr[l], br[l], xlb, xrb, n);
    edge_attn_kernel<<<(n + 3) / 4, 256, 0, stream>>>(xlb, xrb, row_off, csr_src,
                                                      att[l], bias[l], outs[l], n,
                                                      (l < 2) ? 1 : 0);
    hin = outs[l];
  }

  // pool + MLP head
  pool_mlp_kernel<<<n_graphs, 128, 0, stream>>>(hin, batch, n, W4, b4, W5, b5, W6, b6,
                                                (float*)d_out);
}

// Round 2
// 859.087 us; speedup vs baseline: 1.3599x; 1.3599x over previous
//
#include <hip/hip_runtime.h>
#include <math.h>

// ---------------- device helpers ----------------
__device__ __forceinline__ int dev_lower_bound(const int* __restrict__ a, int n, int v){
  int lo = 0, hi = n;
  while (lo < hi){ int mid = (lo + hi) >> 1; if (a[mid] < v) lo = mid + 1; else hi = mid; }
  return lo;
}

// ---------------- CSR build ----------------
__global__ void init_deg_kernel(int* __restrict__ deg, int n){
  int i = blockIdx.x * blockDim.x + threadIdx.x;
  if (i < n) deg[i] = 1;            // self-loop contributes 1 to every node
}

__global__ void hist_kernel(const int* __restrict__ dst, int* __restrict__ deg, int nE){
  int e = blockIdx.x * blockDim.x + threadIdx.x;
  if (e < nE) atomicAdd(&deg[dst[e]], 1);
}

__global__ __launch_bounds__(1024) void scan_kernel(const int* __restrict__ deg,
    int* __restrict__ row_off, int* __restrict__ cursor, int n){
  __shared__ int sums[1024];
  int tid = threadIdx.x;
  int chunk = (n + 1023) >> 10;
  int beg = tid * chunk;
  int end = min(beg + chunk, n);
  int s = 0;
  for (int i = beg; i < end; ++i) s += deg[i];
  sums[tid] = s;
  __syncthreads();
  for (int off = 1; off < 1024; off <<= 1){
    int v = (tid >= off) ? sums[tid - off] : 0;
    __syncthreads();
    sums[tid] += v;
    __syncthreads();
  }
  int run = (tid == 0) ? 0 : sums[tid - 1];
  for (int i = beg; i < end; ++i){ row_off[i] = run; cursor[i] = run; run += deg[i]; }
  if (tid == 0) row_off[n] = sums[1023];
}

__global__ void scatter_kernel(const int* __restrict__ src, const int* __restrict__ dst,
    int* __restrict__ cursor, int* __restrict__ csr_src, int nE, int n){
  int e = blockIdx.x * blockDim.x + threadIdx.x;
  if (e < nE){
    int pos = atomicAdd(&cursor[dst[e]], 1);
    csr_src[pos] = src[e];
  } else if (e < nE + n){
    int i = e - nE;                  // self loop i -> i
    int pos = atomicAdd(&cursor[i], 1);
    csr_src[pos] = i;
  }
}

// ---------------- fused xl/xr GEMM: out = X @ W + b ----------------
__global__ __launch_bounds__(512) void gemm_xlxr_kernel(
    const float* __restrict__ X,
    const float* __restrict__ Wl, const float* __restrict__ bl,
    const float* __restrict__ Wr, const float* __restrict__ br,
    float* __restrict__ xl, float* __restrict__ xr, int n)
{
  const float* W; const float* b; float* out;
  if (blockIdx.y == 0){ W = Wl; b = bl; out = xl; } else { W = Wr; b = br; out = xr; }
  __shared__ float Ws[32][128];      // 16 KB
  __shared__ float Xs[128][36];      // 18.4 KB
  const int tid = threadIdx.x;
  const int row0 = blockIdx.x * 128;
  const int tc = tid & 31;           // 4 output cols
  const int tr = tid >> 5;           // 8 rows
  float acc[8][4] = {};
  for (int kc = 0; kc < 128; kc += 32){
    for (int idx = tid; idx < 1024; idx += 512){          // W chunk: 32x128
      int r = idx >> 5, c4 = idx & 31;
      *(float4*)(&Ws[r][c4 * 4]) = *(const float4*)(W + (size_t)(kc + r) * 128 + c4 * 4);
    }
    for (int idx = tid; idx < 1024; idx += 512){          // X chunk: 128x32
      int r = idx >> 3, c4 = idx & 7;
      int grow = row0 + r;
      float4 v = make_float4(0.f, 0.f, 0.f, 0.f);
      if (grow < n) v = *(const float4*)(X + (size_t)grow * 128 + kc + c4 * 4);
      *(float4*)(&Xs[r][c4 * 4]) = v;
    }
    __syncthreads();
    #pragma unroll
    for (int k = 0; k < 32; ++k){
      float4 w = *(const float4*)(&Ws[k][tc * 4]);
      #pragma unroll
      for (int r = 0; r < 8; ++r){
        float xv = Xs[tr * 8 + r][k];
        acc[r][0] = fmaf(xv, w.x, acc[r][0]);
        acc[r][1] = fmaf(xv, w.y, acc[r][1]);
        acc[r][2] = fmaf(xv, w.z, acc[r][2]);
        acc[r][3] = fmaf(xv, w.w, acc[r][3]);
      }
    }
    __syncthreads();
  }
  float4 bv = *(const float4*)(b + tc * 4);
  #pragma unroll
  for (int r = 0; r < 8; ++r){
    int grow = row0 + tr * 8 + r;
    if (grow < n){
      float4 o = make_float4(acc[r][0] + bv.x, acc[r][1] + bv.y,
                             acc[r][2] + bv.z, acc[r][3] + bv.w);
      *(float4*)(out + (size_t)grow * 128 + tc * 4) = o;
    }
  }
}

// ---------------- per-destination online-softmax attention ----------------
// TWO destination nodes per 64-lane wave (one per 32-lane half); each lane owns
// 4 of 128 feature cols (float4). Single pass over in-edges, unroll 2, fully
// branchless online softmax (invalid/tail edges contribute exp(-3e38)=0).
__global__ __launch_bounds__(256) void edge_attn_kernel(
    const float* __restrict__ xl, const float* __restrict__ xr,
    const int* __restrict__ row_off, const int* __restrict__ csr_src,
    const float* __restrict__ att, const float* __restrict__ bias,
    float* __restrict__ out, int n, int do_relu)
{
  const int gtid = blockIdx.x * blockDim.x + threadIdx.x;
  const int wave = gtid >> 6;
  const int lane = threadIdx.x & 63;
  const int node = wave * 2 + (lane >> 5);       // half-wave -> node
  const bool nvalid = node < n;
  const int nc = nvalid ? node : (n - 1);
  const int f4 = (lane & 31) * 4;                // feature base

  const float4 xrv  = *(const float4*)(xr  + (size_t)nc * 128 + f4);
  const float4 attv = *(const float4*)(att + f4);
  const int base = row_off[nc];
  int deg = row_off[nc + 1] - base;
  if (!nvalid) deg = 0;
  const int degO = __shfl_xor(deg, 32);
  const int maxd = max(deg, degO);               // wave-uniform loop bound

  float m = -3.0e38f, s = 0.f;
  float ax = 0.f, ay = 0.f, az = 0.f, aw = 0.f;

  for (int p = 0; p < maxd; p += 2){
    int c0 = max(min(p,     deg - 1), 0);
    int c1 = max(min(p + 1, deg - 1), 0);
    int s0 = csr_src[base + c0];
    int s1 = csr_src[base + c1];
    float4 x0 = *(const float4*)(xl + (size_t)s0 * 128 + f4);
    float4 x1 = *(const float4*)(xl + (size_t)s1 * 128 + f4);

    float t, p0, p1;
    t = x0.x + xrv.x; t = fmaxf(t, 0.2f * t); p0  = t * attv.x;
    t = x0.y + xrv.y; t = fmaxf(t, 0.2f * t); p0 += t * attv.y;
    t = x0.z + xrv.z; t = fmaxf(t, 0.2f * t); p0 += t * attv.z;
    t = x0.w + xrv.w; t = fmaxf(t, 0.2f * t); p0 += t * attv.w;
    t = x1.x + xrv.x; t = fmaxf(t, 0.2f * t); p1  = t * attv.x;
    t = x1.y + xrv.y; t = fmaxf(t, 0.2f * t); p1 += t * attv.y;
    t = x1.z + xrv.z; t = fmaxf(t, 0.2f * t); p1 += t * attv.z;
    t = x1.w + xrv.w; t = fmaxf(t, 0.2f * t); p1 += t * attv.w;
    #pragma unroll
    for (int off = 1; off < 32; off <<= 1){      // per-half reduction
      p0 += __shfl_xor(p0, off);
      p1 += __shfl_xor(p1, off);
    }
    p0 = (p     < deg) ? p0 : -3.0e38f;
    p1 = (p + 1 < deg) ? p1 : -3.0e38f;

    // online softmax update, edge 0
    float mnew  = fmaxf(m, p0);
    float scale = __expf(m - mnew);
    float pp    = __expf(p0 - mnew);
    s  = s  * scale + pp;
    ax = ax * scale + pp * x0.x;
    ay = ay * scale + pp * x0.y;
    az = az * scale + pp * x0.z;
    aw = aw * scale + pp * x0.w;
    m = mnew;
    // edge 1
    mnew  = fmaxf(m, p1);
    scale = __expf(m - mnew);
    pp    = __expf(p1 - mnew);
    s  = s  * scale + pp;
    ax = ax * scale + pp * x1.x;
    ay = ay * scale + pp * x1.y;
    az = az * scale + pp * x1.z;
    aw = aw * scale + pp * x1.w;
    m = mnew;
  }

  if (nvalid){
    const float inv = 1.0f / s;                  // self-loop guarantees s > 0
    const float4 bv = *(const float4*)(bias + f4);
    float ox = ax * inv + bv.x;
    float oy = ay * inv + bv.y;
    float oz = az * inv + bv.z;
    float ow = aw * inv + bv.w;
    if (do_relu){
      ox = fmaxf(ox, 0.f); oy = fmaxf(oy, 0.f);
      oz = fmaxf(oz, 0.f); ow = fmaxf(ow, 0.f);
    }
    *(float4*)(out + (size_t)node * 128 + f4) = make_float4(ox, oy, oz, ow);
  }
}

// ---------------- mean-pool + MLP head ----------------
__global__ __launch_bounds__(128) void pool_mlp_kernel(
    const float* __restrict__ h, const int* __restrict__ batch, int n,
    const float* __restrict__ W4, const float* __restrict__ b4,
    const float* __restrict__ W5, const float* __restrict__ b5,
    const float* __restrict__ W6, const float* __restrict__ b6,
    float* __restrict__ out)
{
  int g = blockIdx.x;
  int t = threadIdx.x;
  __shared__ float gf[128];
  __shared__ float h1[128];
  __shared__ float h2[64];
  int lo = dev_lower_bound(batch, n, g);
  int hi = dev_lower_bound(batch, n, g + 1);
  float ssum = 0.f;
  for (int i = lo; i < hi; ++i) ssum += h[(size_t)i * 128 + t];
  float cnt = (float)(hi - lo);
  gf[t] = ssum / fmaxf(cnt, 1.0f);
  __syncthreads();
  float a = b4[t];
  for (int k = 0; k < 128; ++k) a = fmaf(gf[k], W4[k * 128 + t], a);
  h1[t] = 1.0f / (1.0f + __expf(-a));
  __syncthreads();
  if (t < 64){
    float a5 = b5[t];
    for (int k = 0; k < 128; ++k) a5 = fmaf(h1[k], W5[k * 64 + t], a5);
    h2[t] = 1.0f / (1.0f + __expf(-a5));
  }
  __syncthreads();
  if (t < 2){
    float a6 = b6[t];
    for (int k = 0; k < 64; ++k) a6 = fmaf(h2[k], W6[k * 2 + t], a6);
    out[g * 2 + t] = a6;
  }
}

// ---------------- launcher ----------------
extern "C" void kernel_launch(void* const* d_in, const int* in_sizes, int n_in,
                              void* d_out, int out_size, void* d_ws, size_t ws_size,
                              hipStream_t stream)
{
  const float* x          = (const float*)d_in[0];
  const int*   edge_index = (const int*)d_in[1];
  const int*   batch      = (const int*)d_in[2];
  const int n  = in_sizes[0] / 128;            // 50000
  const int nE = in_sizes[1] / 2;              // 1600000
  const int* esrc = edge_index;
  const int* edst = edge_index + nE;
  const int n_graphs = out_size / 2;           // 512

  const float *Wl[3], *bl[3], *Wr[3], *br[3], *att[3], *bias[3];
  for (int l = 0; l < 3; ++l){
    Wl[l]   = (const float*)d_in[3 + 6 * l + 0];
    bl[l]   = (const float*)d_in[3 + 6 * l + 1];
    Wr[l]   = (const float*)d_in[3 + 6 * l + 2];
    br[l]   = (const float*)d_in[3 + 6 * l + 3];
    att[l]  = (const float*)d_in[3 + 6 * l + 4];
    bias[l] = (const float*)d_in[3 + 6 * l + 5];
  }
  const float* W4 = (const float*)d_in[21]; const float* b4 = (const float*)d_in[22];
  const float* W5 = (const float*)d_in[23]; const float* b5 = (const float*)d_in[24];
  const float* W6 = (const float*)d_in[25]; const float* b6 = (const float*)d_in[26];

  char* ws = (char*)d_ws;
  size_t off = 0;
  auto alloc = [&](size_t bytes) -> void* {
    void* p = ws + off;
    off = (off + bytes + 255) & ~(size_t)255;
    return p;
  };
  int*   row_off = (int*)  alloc((size_t)(n + 1) * sizeof(int));
  int*   deg     = (int*)  alloc((size_t)n * sizeof(int));
  int*   cursor  = (int*)  alloc((size_t)n * sizeof(int));
  int*   csr_src = (int*)  alloc((size_t)(nE + n) * sizeof(int));
  float* xlb     = (float*)alloc((size_t)n * 128 * sizeof(float));
  float* xrb     = (float*)alloc((size_t)n * 128 * sizeof(float));
  float* hC      = (float*)alloc((size_t)n * 128 * sizeof(float));
  float* hD      = (float*)alloc((size_t)n * 128 * sizeof(float));
  (void)ws_size; (void)n_in;

  // CSR build (by destination)
  init_deg_kernel<<<(n + 255) / 256, 256, 0, stream>>>(deg, n);
  hist_kernel<<<(nE + 255) / 256, 256, 0, stream>>>(edst, deg, nE);
  scan_kernel<<<1, 1024, 0, stream>>>(deg, row_off, cursor, n);
  scatter_kernel<<<(nE + n + 255) / 256, 256, 0, stream>>>(esrc, edst, cursor, csr_src, nE, n);

  // 3 GATv2 layers
  const float* hin = x;
  float* outs[3] = { hC, hD, hC };
  const int waves = (n + 1) / 2;               // 2 nodes per wave
  const int ablocks = (waves * 64 + 255) / 256;
  for (int l = 0; l < 3; ++l){
    dim3 ggrid((n + 127) / 128, 2);
    gemm_xlxr_kernel<<<ggrid, 512, 0, stream>>>(hin, Wl[l], bl[l], Wr[l], br[l], xlb, xrb, n);
    edge_attn_kernel<<<ablocks, 256, 0, stream>>>(xlb, xrb, row_off, csr_src,
                                                  att[l], bias[l], outs[l], n,
                                                  (l < 2) ? 1 : 0);
    hin = outs[l];
  }

  pool_mlp_kernel<<<n_graphs, 128, 0, stream>>>(hin, batch, n, W4, b4, W5, b5, W6, b6,
                                                (float*)d_out);
}